// Round 7
// baseline (719.869 us; speedup 1.0000x reference)
//
#include <hip/hip_runtime.h>
#include <math.h>

#define D 128
#define CHK 64
#define NCHUNK 128
#define LSEQ 8192
#define B_LR 0.005f
#define M_LR 0.01f

typedef float f2 __attribute__((ext_vector_type(2)));

// packed fp32 (VOP3P); fma accumulates tied in-place (no marshaling copies)
__device__ __forceinline__ f2 pk_mul(f2 a, f2 b){ f2 d; asm("v_pk_mul_f32 %0, %1, %2" : "=v"(d) : "v"(a), "v"(b)); return d; }
__device__ __forceinline__ void pk_fma_acc(f2 &acc, f2 a, f2 b){ asm("v_pk_fma_f32 %0, %1, %2, %0" : "+v"(acc) : "v"(a), "v"(b)); }

template<int C>
__device__ __forceinline__ float dppx(float x){
  return __int_as_float(__builtin_amdgcn_update_dpp(0, __float_as_int(x), C, 0xF, 0xF, true));
}
__device__ __forceinline__ void pl32swap(float &a, float &b){ asm("v_permlane32_swap_b32 %0, %1" : "+v"(a), "+v"(b)); }
__device__ __forceinline__ void pl16swap(float &a, float &b){ asm("v_permlane16_swap_b32 %0, %1" : "+v"(a), "+v"(b)); }

// transpose-reduce: input a[64] per lane; lane L returns sum over all 64 lanes of a[L].
// In-place swap variant (replay-verified in round 6; lowest VALU cycles measured).
__device__ __forceinline__ float butterfly64(float* a, int lane){
  #pragma unroll
  for (int t = 0; t < 32; ++t){ pl32swap(a[t], a[t+32]); a[t] = a[t] + a[t+32]; }
  #pragma unroll
  for (int t = 0; t < 16; ++t){ pl16swap(a[t], a[t+16]); a[t] = a[t] + a[t+16]; }
  const bool h8 = (lane & 8) != 0, h4 = (lane & 4) != 0, h2 = (lane & 2) != 0, h1 = (lane & 1) != 0;
  #pragma unroll
  for (int t = 0; t < 8; ++t){
    float send = h8 ? a[t] : a[t+8];
    float keep = h8 ? a[t+8] : a[t];
    a[t] = keep + dppx<0x128>(send);                  // row_ror:8 == lane^8
  }
  #pragma unroll
  for (int t = 0; t < 4; ++t){
    float send = h4 ? a[t] : a[t+4];
    float keep = h4 ? a[t+4] : a[t];
    a[t] = keep + __int_as_float(__builtin_amdgcn_ds_swizzle(__float_as_int(send), 0x101F)); // lane^4
  }
  #pragma unroll
  for (int t = 0; t < 2; ++t){
    float send = h2 ? a[t] : a[t+2];
    float keep = h2 ? a[t+2] : a[t];
    a[t] = keep + dppx<0x4E>(send);                   // quad_perm xor2
  }
  float send = h1 ? a[0] : a[1];
  float keep = h1 ? a[1] : a[0];
  return keep + dppx<0xB1>(send);                     // quad_perm xor1
}

__device__ __forceinline__ void gl_lds16(const float* g, float* l){
  __builtin_amdgcn_global_load_lds((const __attribute__((address_space(1))) float*)g,
                                   (__attribute__((address_space(3))) float*)l, 16, 0, 0);
}

// 256-thread blocks (4 waves = 4 rows), 512 blocks: 2 independent barrier groups
// per CU so one block's barrier/vmcnt drain overlaps the other block's compute.
__global__ __launch_bounds__(256, 2) void lfltm_fwd(
    const float* __restrict__ X,
    const float* __restrict__ init_mem,
    const float* __restrict__ init_opt,
    float* __restrict__ out)
{
  __shared__ float xs[2][CHK * D];       // 64 KiB: double-buffered x chunk, linear [c][j]
  __shared__ float es[4][CHK];           //  1 KiB: per-wave e broadcast (wave-private)
  __shared__ float outs[2][CHK * 5];     //  2.5 KiB: out staging, stride 5 (2-way alias, free)

  const int tid  = threadIdx.x;
  const int w    = tid >> 6;             // wave 0..3 -> row within group
  const int lane = tid & 63;             // owns j = {2*lane, 2*lane+1}

  // XCD-aware: all 32 blocks of one batch on one XCD (L2 reuse of X)
  const int bid  = blockIdx.x;
  const int xcd  = bid & 7;
  const int b    = xcd + 8 * ((bid >> 3) & 1);   // batch 0..15
  const int rg   = bid >> 4;                     // row group 0..31
  const int i    = rg * 4 + w;                   // row 0..127

  const float* __restrict__ Xb = X + (size_t)b * (LSEQ * D);
  float* __restrict__ Ob       = out + (size_t)b * (LSEQ * D);

  // per-lane state: mem row pair + opt pair
  f2 m, o;
  m.x = init_mem[i * D + 2*lane];
  m.y = init_mem[i * D + 2*lane + 1];
  o.x = init_opt[i * D + 2*lane];
  o.y = init_opt[i * D + 2*lane + 1];
  f2 u;                                   // delta_i fold: e-dot uses (m - e_i)
  u.x = (2*lane     == i) ? 1.0f : 0.0f;
  u.y = (2*lane + 1 == i) ? 1.0f : 0.0f;

  // prologue: chunk 0 -> buf 0 (async direct-to-LDS); 8192 floats / 256 threads
  #pragma unroll
  for (int r = 0; r < 8; ++r)
    gl_lds16(Xb + (r*256 + tid)*4, &xs[0][(r*256 + tid)*4]);
  __syncthreads();

  for (int ch = 0; ch < NCHUNK; ++ch) {
    const int cur = ch & 1;

    // (a) coalesced store of previous chunk's outputs (all 256 threads)
    if (ch > 0) {
      const int c = tid >> 2, rr = tid & 3;
      Ob[(size_t)((ch-1)*CHK + c)*D + rg*4 + rr] = outs[cur ^ 1][c*5 + rr];
    }

    // (b) prefetch next chunk -> other buffer (in flight across whole compute)
    {
      int chn = ch + 1; if (chn >= NCHUNK) chn = NCHUNK - 1;
      const float* gb = Xb + (size_t)chn * (CHK * D);
      #pragma unroll
      for (int r = 0; r < 8; ++r)
        gl_lds16(gb + (r*256 + tid)*4, &xs[cur ^ 1][(r*256 + tid)*4]);
    }

    // (c) x[token=lane, i] gather from global (VMEM idle; L2-hot)
    const float xci = Xb[(size_t)(ch*CHK + lane)*D + i];

    f2 lr;
    lr.x = 1.0f / (1.0f + __expf(-o.x));
    lr.y = 1.0f / (1.0f + __expf(-o.y));
    const f2 mp = m - u;

    const float* xb = &xs[cur][2*lane];

    // (d) e-pass: partial dots -> butterfly => lane c holds e_c
    float arr[CHK];
    #pragma unroll
    for (int c = 0; c < CHK; ++c){
      f2 x2 = *(const f2*)(xb + c*D);      // ds_read_b64, stride 512B
      f2 t  = pk_mul(mp, x2);
      arr[c] = t.x + t.y;
    }
    const float e_own = butterfly64(arr, lane);
    es[w][lane] = e_own;                   // wave-private broadcast buffer

    // (e) sequential token march (r2-verbatim pattern: float4 e broadcast + packed math)
    f2 S; S.x = 0.f; S.y = 0.f;            // S is S' = lr .* cumsum(e x)
    f2 Q; Q.x = 0.f; Q.y = 0.f;
    #pragma unroll
    for (int cg = 0; cg < CHK/4; ++cg){
      float4 e4 = *(const float4*)&es[w][cg*4];      // uniform addr -> LDS broadcast
      #pragma unroll
      for (int uu = 0; uu < 4; ++uu){
        const int c = cg*4 + uu;
        const float ec = (uu==0)?e4.x:(uu==1)?e4.y:(uu==2)?e4.z:e4.w;
        f2 e2; e2.x = ec; e2.y = ec;
        f2 x2 = *(const f2*)(xb + c*D);    // ds_read_b64
        f2 ex = pk_mul(e2, x2);
        pk_fma_acc(S, lr, ex);             // S += lr * e * x   (tied, in-place)
        f2 pt = pk_mul(x2, S);
        pk_fma_acc(Q, ex, ex);             // Q += (e x)^2      (tied, in-place)
        arr[c] = pt.x + pt.y;
      }
    }
    const float p = butterfly64(arr, lane);  // lane c: p_c = sum_j lr_j x_cj S_cj

    // (f) out_c = dot(mem, x_c) - B_LR*p_c = e_c + x_ci - B_LR*p_c
    outs[cur][lane*5 + w] = e_own + xci - B_LR * p;

    // (g) chunk-end state update
    m = m - B_LR * S;
    f2 g = lr - lr * lr;                   // lr*(1-lr)
    o = o - M_LR * (g * Q);

    // (h) single barrier: drains glds (next chunk ready), publishes outs
    __syncthreads();
  }

  // epilogue: final chunk's outputs
  {
    const int c = tid >> 2, rr = tid & 3;
    Ob[(size_t)((NCHUNK-1)*CHK + c)*D + rg*4 + rr] = outs[(NCHUNK-1)&1][c*5 + rr];
  }
}

extern "C" void kernel_launch(void* const* d_in, const int* in_sizes, int n_in,
                              void* d_out, int out_size, void* d_ws, size_t ws_size,
                              hipStream_t stream) {
    const float* X  = (const float*)d_in[0];
    const float* im = (const float*)d_in[1];
    const float* io = (const float*)d_in[2];
    float* O        = (float*)d_out;
    hipLaunchKernelGGL(lfltm_fwd, dim3(512), dim3(256), 0, stream, X, im, io, O);
}

// Round 9
// 716.046 us; speedup vs baseline: 1.0053x; 1.0053x over previous
//
#include <hip/hip_runtime.h>
#include <math.h>

#define D 128
#define CHK 64
#define NCHUNK 128
#define LSEQ 8192
#define B_LR 0.005f
#define M_LR 0.01f

typedef float f2 __attribute__((ext_vector_type(2)));

// packed fp32 (VOP3P); fma accumulate tied in-place (no marshaling copies)
__device__ __forceinline__ f2 pk_mul(f2 a, f2 b){ f2 d; asm("v_pk_mul_f32 %0, %1, %2" : "=v"(d) : "v"(a), "v"(b)); return d; }
__device__ __forceinline__ void pk_fma_acc(f2 &acc, f2 a, f2 b){ asm("v_pk_fma_f32 %0, %1, %2, %0" : "+v"(acc) : "v"(a), "v"(b)); }

template<int C>
__device__ __forceinline__ float dppx(float x){
  return __int_as_float(__builtin_amdgcn_update_dpp(0, __float_as_int(x), C, 0xF, 0xF, true));
}
__device__ __forceinline__ void pl32swap(float &a, float &b){ asm("v_permlane32_swap_b32 %0, %1" : "+v"(a), "+v"(b)); }
__device__ __forceinline__ void pl16swap(float &a, float &b){ asm("v_permlane16_swap_b32 %0, %1" : "+v"(a), "+v"(b)); }

// transpose-reduce: input a[64] per lane; lane L returns sum over all 64 lanes of a[L].
// s32/s16 stages swap in-place (replay-verified r6/r7); s8/s4/s2/s1 exactly as
// the r1-r7 verified form (cndmask keep/send + dpp / ds_swizzle).
__device__ __forceinline__ float butterfly64(float* a, int lane){
  #pragma unroll
  for (int t = 0; t < 32; ++t){ pl32swap(a[t], a[t+32]); a[t] = a[t] + a[t+32]; }
  #pragma unroll
  for (int t = 0; t < 16; ++t){ pl16swap(a[t], a[t+16]); a[t] = a[t] + a[t+16]; }
  const bool h8 = (lane & 8) != 0, h4 = (lane & 4) != 0, h2 = (lane & 2) != 0, h1 = (lane & 1) != 0;
  #pragma unroll
  for (int t = 0; t < 8; ++t){
    float send = h8 ? a[t] : a[t+8];
    float keep = h8 ? a[t+8] : a[t];
    a[t] = keep + dppx<0x128>(send);                  // row_ror:8 == lane^8
  }
  #pragma unroll
  for (int t = 0; t < 4; ++t){
    float send = h4 ? a[t] : a[t+4];
    float keep = h4 ? a[t+4] : a[t];
    a[t] = keep + __int_as_float(__builtin_amdgcn_ds_swizzle(__float_as_int(send), 0x101F)); // lane^4
  }
  #pragma unroll
  for (int t = 0; t < 2; ++t){
    float send = h2 ? a[t] : a[t+2];
    float keep = h2 ? a[t+2] : a[t];
    a[t] = keep + dppx<0x4E>(send);                   // quad_perm xor2
  }
  float send = h1 ? a[0] : a[1];
  float keep = h1 ? a[1] : a[0];
  return keep + dppx<0xB1>(send);                     // quad_perm xor1
}

__device__ __forceinline__ void gl_lds16(const float* g, float* l){
  __builtin_amdgcn_global_load_lds((const __attribute__((address_space(1))) float*)g,
                                   (__attribute__((address_space(3))) float*)l, 16, 0, 0);
}

__global__ __launch_bounds__(512, 1) void lfltm_fwd(
    const float* __restrict__ X,
    const float* __restrict__ init_mem,
    const float* __restrict__ init_opt,
    float* __restrict__ out)
{
  __shared__ float xs[2][CHK * D];       // 64 KiB: double-buffered x chunk, linear [c][j]
  __shared__ float es[8][CHK];           //  2 KiB: per-wave e broadcast (wave-private)
  __shared__ float outs[2][CHK * 9];     // out staging, pad 9 (2-way bank alias only)

  const int tid  = threadIdx.x;
  const int w    = tid >> 6;             // wave -> row within group
  const int lane = tid & 63;             // owns j = {2*lane, 2*lane+1}

  // XCD-aware: all blocks of one batch on one XCD (L2 reuse of X)
  const int bid  = blockIdx.x;
  const int xcd  = bid & 7;
  const int slot = bid >> 3;
  const int b    = xcd + 8 * (slot & 1);
  const int rg   = slot >> 1;
  const int i    = rg * 8 + w;

  const float* __restrict__ Xb = X + (size_t)b * (LSEQ * D);
  float* __restrict__ Ob       = out + (size_t)b * (LSEQ * D);

  // per-lane state: mem row pair + opt pair
  f2 m, o;
  m.x = init_mem[i * D + 2*lane];
  m.y = init_mem[i * D + 2*lane + 1];
  o.x = init_opt[i * D + 2*lane];
  o.y = init_opt[i * D + 2*lane + 1];
  f2 u;                                   // delta_i fold: e-dot uses (m - e_i)
  u.x = (2*lane     == i) ? 1.0f : 0.0f;
  u.y = (2*lane + 1 == i) ? 1.0f : 0.0f;

  // prologue: chunk 0 -> buf 0 (async direct-to-LDS)
  #pragma unroll
  for (int r = 0; r < 4; ++r)
    gl_lds16(Xb + (r*512 + tid)*4, &xs[0][(r*512 + tid)*4]);
  __syncthreads();

  for (int ch = 0; ch < NCHUNK; ++ch) {
    const int cur = ch & 1;

    // (a) coalesced store of previous chunk's outputs
    if (ch > 0) {
      const int c = tid >> 3, ww = tid & 7;
      Ob[(size_t)((ch-1)*CHK + c)*D + rg*8 + ww] = outs[cur ^ 1][c*9 + ww];
    }

    // (b) prefetch next chunk -> other buffer (in flight across whole compute)
    {
      int chn = ch + 1; if (chn >= NCHUNK) chn = NCHUNK - 1;
      const float* gb = Xb + (size_t)chn * (CHK * D);
      #pragma unroll
      for (int r = 0; r < 4; ++r)
        gl_lds16(gb + (r*512 + tid)*4, &xs[cur ^ 1][(r*512 + tid)*4]);
    }

    // (c) x[token=lane, i] gather from global (VMEM idle; L2-hot)
    const float xci = Xb[(size_t)(ch*CHK + lane)*D + i];

    f2 lr;
    lr.x = 1.0f / (1.0f + __expf(-o.x));
    lr.y = 1.0f / (1.0f + __expf(-o.y));
    const f2 mp = m - u;

    const float* xb = &xs[cur][2*lane];

    // (d) e-pass: partial dots -> butterfly => lane c holds e_c
    float arr[CHK];
    #pragma unroll
    for (int c = 0; c < CHK; ++c){
      f2 x2 = *(const f2*)(xb + c*D);      // ds_read_b64, stride 512B
      f2 t  = pk_mul(mp, x2);
      arr[c] = t.x + t.y;
    }
    const float e_own = butterfly64(arr, lane);
    es[w][lane] = e_own;                   // wave-private broadcast buffer (in-order DS)

    // (e) sequential token march: float4 e broadcast + packed math, tied accs
    f2 S; S.x = 0.f; S.y = 0.f;            // S is S' = lr .* cumsum(e x)
    f2 Q; Q.x = 0.f; Q.y = 0.f;
    #pragma unroll
    for (int cg = 0; cg < CHK/4; ++cg){
      float4 e4 = *(const float4*)&es[w][cg*4];      // uniform addr -> LDS broadcast
      #pragma unroll
      for (int uu = 0; uu < 4; ++uu){
        const int c = cg*4 + uu;
        const float ec = (uu==0)?e4.x:(uu==1)?e4.y:(uu==2)?e4.z:e4.w;
        f2 e2; e2.x = ec; e2.y = ec;
        f2 x2 = *(const f2*)(xb + c*D);    // ds_read_b64
        f2 ex = pk_mul(e2, x2);
        pk_fma_acc(S, lr, ex);             // S += lr * e * x   (tied, in-place)
        f2 pt = pk_mul(x2, S);
        pk_fma_acc(Q, ex, ex);             // Q += (e x)^2      (tied, in-place)
        arr[c] = pt.x + pt.y;
      }
    }
    const float p = butterfly64(arr, lane);  // lane c: p_c = sum_j lr_j x_cj S_cj

    // (f) out_c = dot(mem, x_c) - B_LR*p_c = e_c + x_ci - B_LR*p_c
    outs[cur][lane*9 + w] = e_own + xci - B_LR * p;

    // (g) chunk-end state update
    m = m - B_LR * S;
    f2 g = lr - lr * lr;                   // lr*(1-lr)
    o = o - M_LR * (g * Q);

    // (h) single barrier: drains glds (next chunk ready), publishes outs
    __syncthreads();
  }

  // epilogue: final chunk's outputs
  {
    const int c = tid >> 3, ww = tid & 7;
    Ob[(size_t)((NCHUNK-1)*CHK + c)*D + rg*8 + ww] = outs[(NCHUNK-1)&1][c*9 + ww];
  }
}

extern "C" void kernel_launch(void* const* d_in, const int* in_sizes, int n_in,
                              void* d_out, int out_size, void* d_ws, size_t ws_size,
                              hipStream_t stream) {
    const float* X  = (const float*)d_in[0];
    const float* im = (const float*)d_in[1];
    const float* io = (const float*)d_in[2];
    float* O        = (float*)d_out;
    hipLaunchKernelGGL(lfltm_fwd, dim3(256), dim3(512), 0, stream, X, im, io, O);
}

// Round 10
// 677.738 us; speedup vs baseline: 1.0622x; 1.0565x over previous
//
#include <hip/hip_runtime.h>
#include <math.h>

#define D 128
#define CHK 64
#define NCHUNK 128
#define LSEQ 8192
#define B_LR 0.005f
#define M_LR 0.01f

template<int C>
__device__ __forceinline__ float dppx(float x){
  return __int_as_float(__builtin_amdgcn_update_dpp(0, __float_as_int(x), C, 0xF, 0xF, true));
}
__device__ __forceinline__ void pl32swap(float &a, float &b){ asm("v_permlane32_swap_b32 %0, %1" : "+v"(a), "+v"(b)); }
__device__ __forceinline__ void pl16swap(float &a, float &b){ asm("v_permlane16_swap_b32 %0, %1" : "+v"(a), "+v"(b)); }

// transpose-reduce: input a[64] per lane; lane L returns sum over all 64 lanes of a[L].
// Champion (r1/r2) form verbatim: cndmask keep/send + dpp / ds_swizzle.
__device__ __forceinline__ float butterfly64(float* a, int lane){
  #pragma unroll
  for (int t = 0; t < 32; ++t){ float u=a[t], w=a[t+32]; pl32swap(u,w); a[t]=u+w; }
  #pragma unroll
  for (int t = 0; t < 16; ++t){ float u=a[t], w=a[t+16]; pl16swap(u,w); a[t]=u+w; }
  const bool h8 = (lane & 8) != 0, h4 = (lane & 4) != 0, h2 = (lane & 2) != 0, h1 = (lane & 1) != 0;
  #pragma unroll
  for (int t = 0; t < 8; ++t){
    float send = h8 ? a[t] : a[t+8];
    float keep = h8 ? a[t+8] : a[t];
    a[t] = keep + dppx<0x128>(send);                  // row_ror:8 == lane^8
  }
  #pragma unroll
  for (int t = 0; t < 4; ++t){
    float send = h4 ? a[t] : a[t+4];
    float keep = h4 ? a[t+4] : a[t];
    a[t] = keep + __int_as_float(__builtin_amdgcn_ds_swizzle(__float_as_int(send), 0x101F)); // lane^4
  }
  #pragma unroll
  for (int t = 0; t < 2; ++t){
    float send = h2 ? a[t] : a[t+2];
    float keep = h2 ? a[t+2] : a[t];
    a[t] = keep + dppx<0x4E>(send);                   // quad_perm xor2
  }
  float send = h1 ? a[0] : a[1];
  float keep = h1 ? a[1] : a[0];
  return keep + dppx<0xB1>(send);                     // quad_perm xor1
}

__device__ __forceinline__ void gl_lds16(const float* g, float* l){
  __builtin_amdgcn_global_load_lds((const __attribute__((address_space(1))) float*)g,
                                   (__attribute__((address_space(3))) float*)l, 16, 0, 0);
}

// 512 threads = 8 waves = 4 rows x 2 j-halves; 512 blocks; 2 blocks/CU co-resident
// (LDS 72.5 KB, VGPR <= 128 via launch_bounds) -> 16 waves/CU = 4 waves/SIMD.
__global__ __launch_bounds__(512, 4) void lfltm_fwd(
    const float* __restrict__ X,
    const float* __restrict__ init_mem,
    const float* __restrict__ init_opt,
    float* __restrict__ out)
{
  __shared__ float xs[2][CHK * D];   // 65536 B: double-buffered x chunk, linear [c][j]
  __shared__ float ebuf[8][CHK];     //  2048 B: per-wave e partials (partner = w^1)
  __shared__ float esb[8][CHK];      //  2048 B: per-wave FULL-e broadcast (march float4 reads)
  __shared__ float pbuf[8][CHK];     //  2048 B: per-wave p partials
  __shared__ float outs[2][CHK * 5]; //  2560 B: out staging, stride 5 (conflict-benign)

  const int tid  = threadIdx.x;
  const int w    = tid >> 6;         // wave 0..7
  const int lane = tid & 63;
  const int r    = w >> 1;           // row within block 0..3
  const int h    = w & 1;            // j-half 0/1 (partner wave = w^1)

  // XCD-aware: all 32 blocks of one batch on one XCD (L2 reuse of X)
  const int bid = blockIdx.x;
  const int xcd = bid & 7;
  const int b   = xcd + 8 * ((bid >> 3) & 1);  // batch 0..15
  const int rg  = bid >> 4;                    // row group 0..31
  const int i   = rg * 4 + r;                  // row 0..127
  const int jl  = h * 64 + lane;               // owned j (one float per lane)

  const float* __restrict__ Xb = X + (size_t)b * (LSEQ * D);
  float* __restrict__ Ob       = out + (size_t)b * (LSEQ * D);

  // per-lane state: one (i, jl) parameter
  float m = init_mem[i * D + jl];
  float o = init_opt[i * D + jl];
  const float u = (jl == i) ? 1.0f : 0.0f;     // delta_i fold: e-dot uses (m - e_i)

  // prologue: chunk 0 -> buf 0 (async direct-to-LDS); 8192 floats / 512 threads
  #pragma unroll
  for (int k = 0; k < 4; ++k)
    gl_lds16(Xb + (k*512 + tid)*4, &xs[0][(k*512 + tid)*4]);
  __syncthreads();

  for (int ch = 0; ch < NCHUNK; ++ch) {
    const int cur = ch & 1;

    // (a) coalesced store of previous chunk's outputs (first 4 waves)
    if (ch > 0 && tid < 256) {
      const int c = tid >> 2, rr = tid & 3;
      Ob[(size_t)((ch-1)*CHK + c)*D + rg*4 + rr] = outs[cur ^ 1][c*5 + rr];
    }

    // (b) prefetch next chunk -> other buffer (latency hidden under e-pass)
    {
      int chn = ch + 1; if (chn >= NCHUNK) chn = NCHUNK - 1;
      const float* gb = Xb + (size_t)chn * (CHK * D);
      #pragma unroll
      for (int k = 0; k < 4; ++k)
        gl_lds16(gb + (k*512 + tid)*4, &xs[cur ^ 1][(k*512 + tid)*4]);
    }

    // (c) x[token=lane, i] gather (uniform across waves; used by h==0 for output)
    const float xci = Xb[(size_t)(ch*CHK + lane)*D + i];

    const float lr = 1.0f / (1.0f + __expf(-o));
    const float mp = m - u;

    const float* xcol = &xs[cur][jl];            // this lane's j-column, stride D

    // (d) e-pass: partial dot over this wave's 64 j's -> butterfly
    float arr[CHK];
    #pragma unroll
    for (int c = 0; c < CHK; ++c)
      arr[c] = mp * xcol[c*D];                   // ds_read_b32, 2-way bank alias (free)
    const float epart = butterfly64(arr, lane);

    // (e) cross-wave e combine: per-wave slot, partner = w^1
    ebuf[w][lane] = epart;
    __syncthreads();                             // barrier A (publishes ebuf; drains glds)
    const float efull = epart + ebuf[w ^ 1][lane];   // full e_{t=lane}
    esb[w][lane] = efull;                        // wave-private broadcast (in-order DS)

    // (f) sequential token march — champion float4-es pattern, scalar math
    float S = 0.f, Q = 0.f;                      // S is S' = lr * cumsum(e x)
    #pragma unroll
    for (int cg = 0; cg < CHK/4; ++cg){
      float4 e4 = *(const float4*)&esb[w][cg*4]; // uniform addr -> LDS broadcast
      #pragma unroll
      for (int uu = 0; uu < 4; ++uu){
        const int c = cg*4 + uu;
        const float ec = (uu==0)?e4.x:(uu==1)?e4.y:(uu==2)?e4.z:e4.w;
        const float x  = xcol[c*D];
        const float ex = ec * x;
        S = fmaf(lr, ex, S);
        arr[c] = x * S;
        Q = fmaf(ex, ex, Q);
      }
    }
    const float ppart = butterfly64(arr, lane);  // lane c: partial p_c over this half's j's

    // (g) cross-wave p combine + output (h==0 finishes)
    pbuf[w][lane] = ppart;
    __syncthreads();                             // barrier B (publishes pbuf)
    if (h == 0) {
      const float p = ppart + pbuf[w ^ 1][lane];
      outs[cur][lane*5 + r] = efull + xci - B_LR * p;
    }

    // (h) chunk-end state update (lane-local)
    m = fmaf(-B_LR, S, m);
    o = fmaf(-M_LR * lr * (1.f - lr), Q, o);

    // (i) barrier C: next chunk staged, outs visible for (a)
    __syncthreads();
  }

  // epilogue: final chunk's outputs
  if (tid < 256) {
    const int c = tid >> 2, rr = tid & 3;
    Ob[(size_t)((NCHUNK-1)*CHK + c)*D + rg*4 + rr] = outs[(NCHUNK-1) & 1][c*5 + rr];
  }
}

extern "C" void kernel_launch(void* const* d_in, const int* in_sizes, int n_in,
                              void* d_out, int out_size, void* d_ws, size_t ws_size,
                              hipStream_t stream) {
    const float* X  = (const float*)d_in[0];
    const float* im = (const float*)d_in[1];
    const float* io = (const float*)d_in[2];
    float* O        = (float*)d_out;
    hipLaunchKernelGGL(lfltm_fwd, dim3(512), dim3(512), 0, stream, X, im, io, O);
}